// Round 1
// baseline (420670.117 us; speedup 1.0000x reference)
//
#include <hip/hip_runtime.h>
#include <hip/hip_bf16.h>

// Persistent-kernel seq2seq (enc LSTM -> attn decoder -> CE loss) for MI355X.
// 256 WGs x 256 thr, 1 WG/CU (152KB LDS), hand-rolled device-scope grid barrier.

#define NWG 256
#define NT  256

typedef unsigned short u16;
typedef unsigned int   u32;
typedef __attribute__((ext_vector_type(4))) float f4;
typedef __attribute__((ext_vector_type(8))) short s8;

constexpr int Bv = 128, Lc = 512, Le = 512, Hd = 512, Vc = 128;
constexpr int KE = 640;   // enc gate GEMM K = V + H
constexpr int KD = 1152;  // dec gate GEMM K = V + H + H

// ---- workspace layout (bytes) ----
constexpr size_t O_WENC = 256;                                   // bf16 [2048][640]
constexpr size_t O_WDEC = O_WENC + (size_t)2048*KE*2;            // bf16 [2048][1152]
constexpr size_t O_ATTW = O_WDEC + (size_t)2048*KD*2;            // bf16 [512][512]
constexpr size_t O_OUTW = O_ATTW + (size_t)512*512*2;            // bf16 [512][1024]
constexpr size_t O_VOCW = O_OUTW + (size_t)512*1024*2;           // bf16 [128][512]
constexpr size_t O_BE   = O_VOCW + (size_t)128*512*2;            // f32 [2048]
constexpr size_t O_BD   = O_BE + 2048*4;                         // f32 [2048]
constexpr size_t O_H    = O_BD + 2048*4;                         // bf16 [2][128][512] ping-pong
constexpr size_t O_VPRV = O_H + (size_t)2*128*512*2;             // bf16 [128][512]
constexpr size_t O_Q    = O_VPRV + (size_t)128*512*2;            // f32 [128][512]
constexpr size_t O_ATTN = O_Q + (size_t)128*512*4;               // bf16 [128][512]
constexpr size_t O_TANH = O_ATTN + (size_t)128*512*2;            // bf16 [128][512]
constexpr size_t O_PFX  = O_TANH + (size_t)128*512*2;            // u32 [128][512]
constexpr size_t O_CNT  = O_PFX + (size_t)128*512*4;             // u32 [128]
constexpr size_t O_PM   = O_CNT + 512;                           // f32 [256]
constexpr size_t O_PS   = O_PM + 1024;                           // f32 [256]
constexpr size_t O_PACC = O_PS + 1024;                           // f32 [256][512]
constexpr size_t O_LOSS = O_PACC + (size_t)256*512*4;            // f32 [2]
constexpr size_t O_ENC  = O_LOSS + 256;                          // bf16 [128][512][512] compacted
constexpr size_t WS_NEED= O_ENC + (size_t)128*512*512*2;         // ~78 MB

// ---- LDS layout ----
constexpr int SM_U     = 64*KD*2;         // 147456: weight slice region end
constexpr int SM_BYTES = SM_U + 8192;     // union: exch(8K) | q(2K)+scores(1K)+red | logits(8K)

struct P {
  const float *C; const int *Cpad; const int *E; const float *Eemb;
  const float *eWih,*eWhh,*ebih,*ebhh;
  const float *dWih,*dWhh,*dbih,*dbhh;
  const float *attW,*outW,*outb,*vocW,*vocb;
  char* ws; float* out;
};

__device__ inline u16 f2bf(float x){
  u32 u = __float_as_uint(x);
  u32 r = (u + 0x7fffu + ((u>>16)&1u)) >> 16;
  return (u16)r;
}
__device__ inline float bf2f(u16 b){ return __uint_as_float(((u32)b)<<16); }
__device__ inline float sigm(float x){ return 1.f/(1.f+expf(-x)); }

__device__ inline f4 MM(s8 a, s8 b, f4 c){
  return __builtin_amdgcn_mfma_f32_16x16x32_bf16(a, b, c, 0, 0, 0);
}

// on-the-fly f32 -> bf16 A fragment (8 contiguous k)
__device__ inline s8 cvt8(const float* p){
  f4 u = *(const f4*)p, v = *(const f4*)(p+4);
  s8 r;
  r[0]=(short)f2bf(u[0]); r[1]=(short)f2bf(u[1]); r[2]=(short)f2bf(u[2]); r[3]=(short)f2bf(u[3]);
  r[4]=(short)f2bf(v[0]); r[5]=(short)f2bf(v[1]); r[6]=(short)f2bf(v[2]); r[7]=(short)f2bf(v[3]);
  return r;
}

// B fragment read from XOR-swizzled LDS weight slice [64][K]
__device__ inline s8 ldsB(const char* sm, int K, int srow, int k){
  int byte = srow*(K*2) + k*2;
  byte ^= (srow&7)<<4;
  return *(const s8*)(sm + byte);
}

__device__ inline float wredmax(float v){
  #pragma unroll
  for (int m=32;m;m>>=1) v = fmaxf(v, __shfl_xor(v,m,64));
  return v;
}
__device__ inline float wredsum(float v){
  #pragma unroll
  for (int m=32;m;m>>=1) v += __shfl_xor(v,m,64);
  return v;
}

extern "C" __global__ void __launch_bounds__(NT,1) k_main(P p)
{
  extern __shared__ char sm[];
  const int wg = blockIdx.x, tid = threadIdx.x;
  const int gt = wg*NT + tid;

  char* ws = p.ws;
  u32*  bar  = (u32*)ws;
  u16*  wenc = (u16*)(ws + O_WENC);
  u16*  wdec = (u16*)(ws + O_WDEC);
  u16*  attw = (u16*)(ws + O_ATTW);
  u16*  outw = (u16*)(ws + O_OUTW);
  u16*  vocw = (u16*)(ws + O_VOCW);
  float* be  = (float*)(ws + O_BE);
  float* bd  = (float*)(ws + O_BD);
  u16*  hbf  = (u16*)(ws + O_H);
  u16*  vpv  = (u16*)(ws + O_VPRV);
  float* qg  = (float*)(ws + O_Q);
  u16*  attnb= (u16*)(ws + O_ATTN);
  u16*  tnh  = (u16*)(ws + O_TANH);
  u32*  pfx  = (u32*)(ws + O_PFX);
  u32*  cntp = (u32*)(ws + O_CNT);
  float* pm  = (float*)(ws + O_PM);
  float* ps  = (float*)(ws + O_PS);
  float* pacc= (float*)(ws + O_PACC);
  float* losp= (float*)(ws + O_LOSS);
  u16*  encc = (u16*)(ws + O_ENC);

  u32 gen = 0;
  auto GB = [&](){
    gen++;
    __threadfence();
    __syncthreads();
    if (tid == 0){
      __hip_atomic_fetch_add(bar, 1u, __ATOMIC_RELEASE, __HIP_MEMORY_SCOPE_AGENT);
      while (__hip_atomic_load(bar, __ATOMIC_ACQUIRE, __HIP_MEMORY_SCOPE_AGENT) < gen*(u32)NWG)
        __builtin_amdgcn_s_sleep(1);
    }
    __syncthreads();
    __threadfence();
  };

  // ================= phase 0: pack/convert/init =================
  for (int i = gt; i < 2048*KE; i += NWG*NT){
    int row = i / KE, k = i - row*KE;
    float v = (k < 128) ? p.eWih[row*128 + k] : p.eWhh[row*512 + (k-128)];
    wenc[i] = f2bf(v);
  }
  for (int i = gt; i < 2048*KD; i += NWG*NT){
    int row = i / KD, k = i - row*KD;
    float v = (k < 640) ? p.dWih[row*640 + k] : p.dWhh[row*512 + (k-640)];
    wdec[i] = f2bf(v);
  }
  for (int i = gt; i < 512*512;  i += NWG*NT) attw[i] = f2bf(p.attW[i]);
  for (int i = gt; i < 512*1024; i += NWG*NT) outw[i] = f2bf(p.outW[i]);
  for (int i = gt; i < 128*512;  i += NWG*NT) vocw[i] = f2bf(p.vocW[i]);
  for (int i = gt; i < 2048;     i += NWG*NT){ be[i] = p.ebih[i]+p.ebhh[i]; bd[i] = p.dbih[i]+p.dbhh[i]; }
  { u32* hz = (u32*)hbf; for (int i = gt; i < 65536; i += NWG*NT) hz[i] = 0; }
  { u32* vz = (u32*)vpv; for (int i = gt; i < 32768; i += NWG*NT) vz[i] = 0; }
  if (gt == 0){ losp[0] = 0.f; losp[1] = 0.f; }
  if (wg < 128){
    int* padl = (int*)(sm + SM_U);
    for (int i = tid; i < 512; i += NT) padl[i] = p.Cpad[wg*512 + i];
    __syncthreads();
    if (tid == 0){
      u32 run = 0;
      for (int tt = 0; tt < 512; tt++){ pfx[wg*512+tt] = run; if (padl[tt] == 0) run++; }
      cntp[wg] = run;
    }
    __syncthreads();
  }
  GB();

  // persistent ownership
  const int rg = wg >> 5, cg = wg & 31;   // 8 rowgroups x 32 colgroups
  const int l  = tid & 63, wv = tid >> 6;
  const int n2 = wv >> 1, k2 = wv & 1;    // wave roles: gate-pair x K-half
  const int kl = (l>>4) << 3;
  const int ar = rg*16 + (l&15);          // A row (batch)
  float cst = 0.f;                        // cell state, this thread owns (row,unit)
  float accN = 0.f, accC = 0.f;

  // ================= encoder =================
  { // preload enc weight slice to LDS (XOR swizzle)
    const int chunks = KE/8;
    for (int idx = tid; idx < 64*chunks; idx += NT){
      int s = idx / chunks, cc = idx - s*chunks;
      int grow = (s>>4)*512 + cg*16 + (s&15);
      uint4 v = *(const uint4*)(wenc + (size_t)grow*KE + cc*8);
      int byte = s*(KE*2) + cc*16; byte ^= (s&7)<<4;
      *(uint4*)(sm + byte) = v;
    }
  }
  __syncthreads();

  for (int t = 0; t < Lc; t++){
    const u16* hold = hbf + (t&1)*Bv*Hd;
    u16* hnew       = hbf + ((t+1)&1)*Bv*Hd;
    f4 acc0 = {0.f,0.f,0.f,0.f}, acc1 = {0.f,0.f,0.f,0.f};
    for (int ks = 0; ks < 10; ks++){
      int k = k2*320 + ks*32 + kl;
      s8 a;
      if (k < 128) a = cvt8(p.C + ((size_t)ar*Lc + t)*Vc + k);
      else         a = *(const s8*)(hold + ar*Hd + (k-128));
      acc0 = MM(a, ldsB(sm, KE, (n2*2+0)*16 + (l&15), k), acc0);
      acc1 = MM(a, ldsB(sm, KE, (n2*2+1)*16 + (l&15), k), acc1);
    }
    float* exch = (float*)(sm + SM_U);
    #pragma unroll
    for (int r = 0; r < 4; r++){
      int row = ((l>>4)<<2) + r;
      exch[((k2*4 + n2*2+0)*16 + row)*16 + (l&15)] = acc0[r];
      exch[((k2*4 + n2*2+1)*16 + row)*16 + (l&15)] = acc1[r];
    }
    __syncthreads();
    {
      int row = tid >> 4, u = tid & 15;
      int gb = cg*16 + u;
      float gi = exch[((0)*16+row)*16+u] + exch[((4)*16+row)*16+u] + be[0*512+gb];
      float gf = exch[((1)*16+row)*16+u] + exch[((5)*16+row)*16+u] + be[1*512+gb];
      float gg = exch[((2)*16+row)*16+u] + exch[((6)*16+row)*16+u] + be[2*512+gb];
      float go = exch[((3)*16+row)*16+u] + exch[((7)*16+row)*16+u] + be[3*512+gb];
      float fi = sigm(gi), ff = sigm(gf), fg = tanhf(gg), fo = sigm(go);
      cst = ff*cst + fi*fg;
      float hn = fo * tanhf(cst);
      int b = rg*16 + row;
      u16 hb = f2bf(hn);
      hnew[b*Hd + gb] = hb;
      if (p.Cpad[b*Lc + t] == 0){
        u32 pos = pfx[b*Lc + t];
        encc[((size_t)b*Lc + pos)*Hd + gb] = hb;
      }
    }
    GB();
  }

  // ================= decoder =================
  { // preload dec weight slice
    const int chunks = KD/8;
    for (int idx = tid; idx < 64*chunks; idx += NT){
      int s = idx / chunks, cc = idx - s*chunks;
      int grow = (s>>4)*512 + cg*16 + (s&15);
      uint4 v = *(const uint4*)(wdec + (size_t)grow*KD + cc*8);
      int byte = s*(KD*2) + cc*16; byte ^= (s&7)<<4;
      *(uint4*)(sm + byte) = v;
    }
  }
  __syncthreads();

  for (int t = 0; t < Le-1; t++){
    const u16* hold = hbf + (t&1)*Bv*Hd;
    u16* hnew       = hbf + ((t+1)&1)*Bv*Hd;

    // ---- S1: gates GEMM + cell ----
    {
      f4 acc0 = {0.f,0.f,0.f,0.f}, acc1 = {0.f,0.f,0.f,0.f};
      for (int ks = 0; ks < 18; ks++){
        int k = k2*576 + ks*32 + kl;
        s8 a;
        if (k < 128)      a = cvt8(p.Eemb + ((size_t)ar*Le + t)*Vc + k);
        else if (k < 640) a = *(const s8*)(vpv  + ar*Hd + (k-128));
        else              a = *(const s8*)(hold + ar*Hd + (k-640));
        acc0 = MM(a, ldsB(sm, KD, (n2*2+0)*16 + (l&15), k), acc0);
        acc1 = MM(a, ldsB(sm, KD, (n2*2+1)*16 + (l&15), k), acc1);
      }
      float* exch = (float*)(sm + SM_U);
      #pragma unroll
      for (int r = 0; r < 4; r++){
        int row = ((l>>4)<<2) + r;
        exch[((k2*4 + n2*2+0)*16 + row)*16 + (l&15)] = acc0[r];
        exch[((k2*4 + n2*2+1)*16 + row)*16 + (l&15)] = acc1[r];
      }
      __syncthreads();
      {
        int row = tid >> 4, u = tid & 15;
        int gb = cg*16 + u;
        float gi = exch[((0)*16+row)*16+u] + exch[((4)*16+row)*16+u] + bd[0*512+gb];
        float gf = exch[((1)*16+row)*16+u] + exch[((5)*16+row)*16+u] + bd[1*512+gb];
        float gg = exch[((2)*16+row)*16+u] + exch[((6)*16+row)*16+u] + bd[2*512+gb];
        float go = exch[((3)*16+row)*16+u] + exch[((7)*16+row)*16+u] + bd[3*512+gb];
        float fi = sigm(gi), ff = sigm(gf), fg = tanhf(gg), fo = sigm(go);
        cst = ff*cst + fi*fg;
        float hn = fo * tanhf(cst);
        hnew[(rg*16+row)*Hd + gb] = f2bf(hn);
      }
    }
    GB();

    // ---- S2: q = h_new @ attW^T ----
    if (tid < 64){
      f4 acc = {0.f,0.f,0.f,0.f};
      for (int ks = 0; ks < 16; ks++){
        int k = ks*32 + kl;
        s8 a  = *(const s8*)(hnew + (rg*16 + (l&15))*Hd + k);
        s8 bb = *(const s8*)(attw + (size_t)(cg*16 + (l&15))*Hd + k);
        acc = MM(a, bb, acc);
      }
      #pragma unroll
      for (int r = 0; r < 4; r++){
        int b = rg*16 + ((l>>4)<<2) + r;
        qg[b*Hd + cg*16 + (l&15)] = acc[r];
      }
    }
    GB();

    // ---- S3: flash attention partials (2 WGs per row) ----
    {
      const int row = wg >> 1, half = wg & 1;
      const int cn = (int)cntp[row], c2 = cn >> 1;
      const int st = half ? c2 : 0, en = half ? cn : c2, n = en - st;
      float* qld = (float*)(sm + SM_U);            // permuted q row
      float* scl = (float*)(sm + SM_U + 2048);     // scores -> weights
      float* red = (float*)(sm + SM_U + 3072);
      for (int i = tid; i < 512; i += NT)
        qld[i] = qg[row*Hd + ((i&31)*16 + (i>>5))];
      __syncthreads();
      const int sub = tid >> 5, ln = tid & 31;
      for (int i = sub; i < n; i += 8){
        const u16* e = encc + ((size_t)row*Lc + st + i)*Hd + ln*16;
        s8 ev0 = *(const s8*)(e);
        s8 ev1 = *(const s8*)(e + 8);
        float s = 0.f;
        #pragma unroll
        for (int j = 0; j < 8; j++) s += bf2f((u16)ev0[j]) * qld[j*32 + ln];
        #pragma unroll
        for (int j = 0; j < 8; j++) s += bf2f((u16)ev1[j]) * qld[(j+8)*32 + ln];
        #pragma unroll
        for (int m = 1; m < 32; m <<= 1) s += __shfl_xor(s, m, 64);
        if (ln == 0) scl[i] = s;
      }
      __syncthreads();
      float mloc = -1e30f;
      for (int i = tid; i < n; i += NT) mloc = fmaxf(mloc, scl[i]);
      mloc = wredmax(mloc);
      if ((tid&63) == 0) red[tid>>6] = mloc;
      __syncthreads();
      float M = fmaxf(fmaxf(red[0],red[1]), fmaxf(red[2],red[3]));
      __syncthreads();
      float sloc = 0.f;
      for (int i = tid; i < n; i += NT){ float w = expf(scl[i]-M); scl[i] = w; sloc += w; }
      sloc = wredsum(sloc);
      if ((tid&63) == 0) red[tid>>6] = sloc;
      __syncthreads();
      float S = red[0]+red[1]+red[2]+red[3];
      float a0 = 0.f, a1 = 0.f;
      const int h0 = tid*2;
      const u16* eb = encc + ((size_t)row*Lc + st)*Hd + h0;
      for (int i = 0; i < n; i++){
        float w = scl[i];
        u32 ev = *(const u32*)(eb + (size_t)i*Hd);
        a0 += w * bf2f((u16)(ev & 0xffffu));
        a1 += w * bf2f((u16)(ev >> 16));
      }
      pacc[(size_t)wg*Hd + h0]   = a0;
      pacc[(size_t)wg*Hd + h0+1] = a1;
      if (tid == 0){ pm[wg] = M; ps[wg] = S; }
    }
    GB();

    // ---- S4: combine + Vnew + logits + CE (8 WGs) ----
    if (wg < 8){
      const int b0 = wg*16;
      float* sc4 = (float*)(sm + SM_U + 3072);
      if (tid < 16){
        int b = b0 + tid;
        float m1 = pm[2*b], m2 = pm[2*b+1], s1 = ps[2*b], s2 = ps[2*b+1];
        float M = fmaxf(m1, m2);
        float e1 = expf(m1-M), e2 = expf(m2-M);
        float den = s1*e1 + s2*e2;
        sc4[tid*2]   = e1/den;
        sc4[tid*2+1] = e2/den;
      }
      __syncthreads();
      for (int idx = tid; idx < 16*512; idx += NT){
        int row = idx >> 9, h = idx & 511, b = b0 + row;
        float v = pacc[(size_t)(2*b)*Hd + h]*sc4[row*2] + pacc[(size_t)(2*b+1)*Hd + h]*sc4[row*2+1];
        attnb[b*Hd + h] = f2bf(v);
      }
      __syncthreads();
      // Vnew = [h, attn] @ outW^T + out_b
      f4 vac[8];
      #pragma unroll
      for (int nn = 0; nn < 8; nn++){
        float ob = p.outb[(wv*8+nn)*16 + (l&15)];
        f4 z = {ob,ob,ob,ob}; vac[nn] = z;
      }
      for (int ks = 0; ks < 32; ks++){
        int k = ks*32 + kl;
        s8 a = (k < 512) ? *(const s8*)(hnew  + (b0+(l&15))*Hd + k)
                         : *(const s8*)(attnb + (b0+(l&15))*Hd + (k-512));
        #pragma unroll
        for (int nn = 0; nn < 8; nn++){
          int ncol = (wv*8+nn)*16 + (l&15);
          s8 bb = *(const s8*)(outw + (size_t)ncol*1024 + k);
          vac[nn] = MM(a, bb, vac[nn]);
        }
      }
      #pragma unroll
      for (int nn = 0; nn < 8; nn++){
        #pragma unroll
        for (int r = 0; r < 4; r++){
          int ncol = (wv*8+nn)*16 + (l&15);
          int b = b0 + ((l>>4)<<2) + r;
          float v = vac[nn][r];
          vpv[b*Hd + ncol] = f2bf(v);
          tnh[b*Hd + ncol] = f2bf(tanhf(v));
        }
      }
      __syncthreads();
      // logits = tanh(Vnew) @ vocW^T + voc_b
      float* lg = (float*)(sm + SM_U);
      f4 lac[2];
      #pragma unroll
      for (int v2 = 0; v2 < 2; v2++){
        float vb = p.vocb[(wv*2+v2)*16 + (l&15)];
        f4 z = {vb,vb,vb,vb}; lac[v2] = z;
      }
      for (int ks = 0; ks < 16; ks++){
        int k = ks*32 + kl;
        s8 a = *(const s8*)(tnh + (b0+(l&15))*Hd + k);
        #pragma unroll
        for (int v2 = 0; v2 < 2; v2++){
          int vcol = (wv*2+v2)*16 + (l&15);
          s8 bb = *(const s8*)(vocw + (size_t)vcol*Hd + k);
          lac[v2] = MM(a, bb, lac[v2]);
        }
      }
      #pragma unroll
      for (int v2 = 0; v2 < 2; v2++){
        #pragma unroll
        for (int r = 0; r < 4; r++){
          int vcol = (wv*2+v2)*16 + (l&15);
          int row = ((l>>4)<<2) + r;
          lg[row*128 + vcol] = lac[v2][r];
        }
      }
      __syncthreads();
      // CE
      {
        int row = tid >> 4, i = tid & 15;
        int b = b0 + row;
        float lm = -1e30f;
        #pragma unroll
        for (int j = 0; j < 8; j++) lm = fmaxf(lm, lg[row*128 + i*8 + j]);
        #pragma unroll
        for (int m = 1; m < 16; m <<= 1) lm = fmaxf(lm, __shfl_xor(lm, m, 64));
        float le = 0.f;
        #pragma unroll
        for (int j = 0; j < 8; j++) le += expf(lg[row*128 + i*8 + j] - lm);
        #pragma unroll
        for (int m = 1; m < 16; m <<= 1) le += __shfl_xor(le, m, 64);
        if (i == 0){
          int tgt = p.E[b*Le + (t+1)];
          float lt = lg[row*128 + tgt];
          if (tgt != 0){ accN += logf(le) + lm - lt; accC += 1.f; }
        }
      }
    }
    GB();
  }

  // ================= loss =================
  if (wg < 8 && (tid&15) == 0){
    atomicAdd(losp + 0, accN);
    atomicAdd(losp + 1, accC);
  }
  GB();
  if (wg == 0 && tid == 0) p.out[0] = losp[0] / fmaxf(losp[1], 1.f);
}

extern "C" void kernel_launch(void* const* d_in, const int* in_sizes, int n_in,
                              void* d_out, int out_size, void* d_ws, size_t ws_size,
                              hipStream_t stream)
{
  hipFuncSetAttribute(reinterpret_cast<const void*>(k_main),
                      hipFuncAttributeMaxDynamicSharedMemorySize, SM_BYTES);
  hipMemsetAsync(d_ws, 0, 256, stream);   // grid-barrier counter reset every call

  P prm;
  prm.C    = (const float*)d_in[0];
  prm.Cpad = (const int*)  d_in[1];
  prm.E    = (const int*)  d_in[2];
  prm.Eemb = (const float*)d_in[3];
  prm.eWih = (const float*)d_in[4];
  prm.eWhh = (const float*)d_in[5];
  prm.ebih = (const float*)d_in[6];
  prm.ebhh = (const float*)d_in[7];
  prm.dWih = (const float*)d_in[8];
  prm.dWhh = (const float*)d_in[9];
  prm.dbih = (const float*)d_in[10];
  prm.dbhh = (const float*)d_in[11];
  prm.attW = (const float*)d_in[12];
  prm.outW = (const float*)d_in[13];
  prm.outb = (const float*)d_in[14];
  prm.vocW = (const float*)d_in[15];
  prm.vocb = (const float*)d_in[16];
  prm.ws   = (char*)d_ws;
  prm.out  = (float*)d_out;

  k_main<<<dim3(NWG), dim3(NT), SM_BYTES, stream>>>(prm);
}

// Round 2
// 90611.047 us; speedup vs baseline: 4.6426x; 4.6426x over previous
//
#include <hip/hip_runtime.h>
#include <hip/hip_bf16.h>

// Persistent-kernel seq2seq (enc LSTM -> attn decoder -> CE loss) for MI355X.
// 256 WGs x 256 thr, 1 WG/CU (152KB LDS).
// R2: barrier overhaul — RELAXED spin (no per-iteration L2 invalidate),
// rowgroup-scoped barriers (32 WGs, rg = wg&7 so a group likely maps to one
// XCD), leader-only release/acquire fences. Only 2 grid-wide barriers total.

#define NWG 256
#define NT  256

typedef unsigned short u16;
typedef unsigned int   u32;
typedef __attribute__((ext_vector_type(4))) float f4;
typedef __attribute__((ext_vector_type(8))) short s8;

constexpr int Bv = 128, Lc = 512, Le = 512, Hd = 512, Vc = 128;
constexpr int KE = 640;   // enc gate GEMM K = V + H
constexpr int KD = 1152;  // dec gate GEMM K = V + H + H

// ---- workspace layout (bytes) ----
// [0,2048): barrier counters. barAll @0; rowgroup rg @ 256 + rg*128.
constexpr size_t O_WENC = 4096;                                  // bf16 [2048][640]
constexpr size_t O_WDEC = O_WENC + (size_t)2048*KE*2;            // bf16 [2048][1152]
constexpr size_t O_ATTW = O_WDEC + (size_t)2048*KD*2;            // bf16 [512][512]
constexpr size_t O_OUTW = O_ATTW + (size_t)512*512*2;            // bf16 [512][1024]
constexpr size_t O_VOCW = O_OUTW + (size_t)512*1024*2;           // bf16 [128][512]
constexpr size_t O_BE   = O_VOCW + (size_t)128*512*2;            // f32 [2048]
constexpr size_t O_BD   = O_BE + 2048*4;                         // f32 [2048]
constexpr size_t O_H    = O_BD + 2048*4;                         // bf16 [2][128][512] ping-pong
constexpr size_t O_VPRV = O_H + (size_t)2*128*512*2;             // bf16 [128][512]
constexpr size_t O_Q    = O_VPRV + (size_t)128*512*2;            // f32 [128][512]
constexpr size_t O_ATTN = O_Q + (size_t)128*512*4;               // bf16 [128][512]
constexpr size_t O_TANH = O_ATTN + (size_t)128*512*2;            // bf16 [128][512]
constexpr size_t O_PFX  = O_TANH + (size_t)128*512*2;            // u32 [128][512]
constexpr size_t O_CNT  = O_PFX + (size_t)128*512*4;             // u32 [128]
constexpr size_t O_PM   = O_CNT + 512;                           // f32 [256] by lid
constexpr size_t O_PS   = O_PM + 1024;                           // f32 [256] by lid
constexpr size_t O_PACC = O_PS + 1024;                           // f32 [256][512] by lid
constexpr size_t O_LOSS = O_PACC + (size_t)256*512*4;            // f32 [2]
constexpr size_t O_ENC  = O_LOSS + 256;                          // bf16 [128][512][512] compacted
constexpr size_t WS_NEED= O_ENC + (size_t)128*512*512*2;         // ~78 MB

// ---- LDS layout ----
constexpr int SM_U     = 64*KD*2;         // 147456: weight slice region end
constexpr int SM_BYTES = SM_U + 8192;     // union: exch(8K) | q(2K)+scores(1K)+red | logits(8K)

struct P {
  const float *C; const int *Cpad; const int *E; const float *Eemb;
  const float *eWih,*eWhh,*ebih,*ebhh;
  const float *dWih,*dWhh,*dbih,*dbhh;
  const float *attW,*outW,*outb,*vocW,*vocb;
  char* ws; float* out;
};

__device__ inline u16 f2bf(float x){
  u32 u = __float_as_uint(x);
  u32 r = (u + 0x7fffu + ((u>>16)&1u)) >> 16;
  return (u16)r;
}
__device__ inline float bf2f(u16 b){ return __uint_as_float(((u32)b)<<16); }
__device__ inline float sigm(float x){ return 1.f/(1.f+expf(-x)); }

__device__ inline f4 MM(s8 a, s8 b, f4 c){
  return __builtin_amdgcn_mfma_f32_16x16x32_bf16(a, b, c, 0, 0, 0);
}

// on-the-fly f32 -> bf16 A fragment (8 contiguous k)
__device__ inline s8 cvt8(const float* p){
  f4 u = *(const f4*)p, v = *(const f4*)(p+4);
  s8 r;
  r[0]=(short)f2bf(u[0]); r[1]=(short)f2bf(u[1]); r[2]=(short)f2bf(u[2]); r[3]=(short)f2bf(u[3]);
  r[4]=(short)f2bf(v[0]); r[5]=(short)f2bf(v[1]); r[6]=(short)f2bf(v[2]); r[7]=(short)f2bf(v[3]);
  return r;
}

// B fragment read from XOR-swizzled LDS weight slice [64][K]
__device__ inline s8 ldsB(const char* sm, int K, int srow, int k){
  int byte = srow*(K*2) + k*2;
  byte ^= (srow&7)<<4;
  return *(const s8*)(sm + byte);
}

__device__ inline float wredmax(float v){
  #pragma unroll
  for (int m=32;m;m>>=1) v = fmaxf(v, __shfl_xor(v,m,64));
  return v;
}
__device__ inline float wredsum(float v){
  #pragma unroll
  for (int m=32;m;m>>=1) v += __shfl_xor(v,m,64);
  return v;
}

extern "C" __global__ void __launch_bounds__(NT,1) k_main(P p)
{
  extern __shared__ char sm[];
  const int wg = blockIdx.x, tid = threadIdx.x;
  const int gt = wg*NT + tid;

  // rowgroup mapping: rg = wg&7 (consecutive blockIdx round-robin across
  // XCDs -> a rowgroup's 32 WGs likely share one XCD; heuristic only).
  const int rg = wg & 7, cg = wg >> 3;
  const int lid = rg*32 + cg;             // logical id for pm/ps/pacc

  char* ws = p.ws;
  u32*  barAll = (u32*)ws;
  u32*  barRG  = (u32*)(ws + 256 + rg*128);
  u16*  wenc = (u16*)(ws + O_WENC);
  u16*  wdec = (u16*)(ws + O_WDEC);
  u16*  attw = (u16*)(ws + O_ATTW);
  u16*  outw = (u16*)(ws + O_OUTW);
  u16*  vocw = (u16*)(ws + O_VOCW);
  float* be  = (float*)(ws + O_BE);
  float* bd  = (float*)(ws + O_BD);
  u16*  hbf  = (u16*)(ws + O_H);
  u16*  vpv  = (u16*)(ws + O_VPRV);
  float* qg  = (float*)(ws + O_Q);
  u16*  attnb= (u16*)(ws + O_ATTN);
  u16*  tnh  = (u16*)(ws + O_TANH);
  u32*  pfx  = (u32*)(ws + O_PFX);
  u32*  cntp = (u32*)(ws + O_CNT);
  float* pm  = (float*)(ws + O_PM);
  float* ps  = (float*)(ws + O_PS);
  float* pacc= (float*)(ws + O_PACC);
  float* losp= (float*)(ws + O_LOSS);
  u16*  encc = (u16*)(ws + O_ENC);

  // Barrier: after __syncthreads() all WG stores are drained to L2 (L1 is
  // write-through), so leader-only release (wbl2) / acquire (inv) suffice.
  // Spin uses RELAXED load: NO per-iteration cache invalidate.
  u32 genA = 0, genG = 0;
  auto BAR = [&](u32* ctr, u32 target){
    __syncthreads();
    if (tid == 0){
      __builtin_amdgcn_fence(__ATOMIC_RELEASE, "agent");
      __hip_atomic_fetch_add(ctr, 1u, __ATOMIC_RELAXED, __HIP_MEMORY_SCOPE_AGENT);
      while (__hip_atomic_load(ctr, __ATOMIC_RELAXED, __HIP_MEMORY_SCOPE_AGENT) < target)
        __builtin_amdgcn_s_sleep(1);
      __builtin_amdgcn_fence(__ATOMIC_ACQUIRE, "agent");
    }
    __syncthreads();
  };
  auto GBall = [&](){ genA++; BAR(barAll, genA*(u32)NWG); };
  auto RGB   = [&](){ genG++; BAR(barRG,  genG*32u); };

  // ================= phase 0: pack/convert/init =================
  for (int i = gt; i < 2048*KE; i += NWG*NT){
    int row = i / KE, k = i - row*KE;
    float v = (k < 128) ? p.eWih[row*128 + k] : p.eWhh[row*512 + (k-128)];
    wenc[i] = f2bf(v);
  }
  for (int i = gt; i < 2048*KD; i += NWG*NT){
    int row = i / KD, k = i - row*KD;
    float v = (k < 640) ? p.dWih[row*640 + k] : p.dWhh[row*512 + (k-640)];
    wdec[i] = f2bf(v);
  }
  for (int i = gt; i < 512*512;  i += NWG*NT) attw[i] = f2bf(p.attW[i]);
  for (int i = gt; i < 512*1024; i += NWG*NT) outw[i] = f2bf(p.outW[i]);
  for (int i = gt; i < 128*512;  i += NWG*NT) vocw[i] = f2bf(p.vocW[i]);
  for (int i = gt; i < 2048;     i += NWG*NT){ be[i] = p.ebih[i]+p.ebhh[i]; bd[i] = p.dbih[i]+p.dbhh[i]; }
  { u32* hz = (u32*)hbf; for (int i = gt; i < 65536; i += NWG*NT) hz[i] = 0; }
  { u32* vz = (u32*)vpv; for (int i = gt; i < 32768; i += NWG*NT) vz[i] = 0; }
  if (gt == 0){ losp[0] = 0.f; losp[1] = 0.f; }
  if (wg < 128){
    int* padl = (int*)(sm + SM_U);
    for (int i = tid; i < 512; i += NT) padl[i] = p.Cpad[wg*512 + i];
    __syncthreads();
    if (tid == 0){
      u32 run = 0;
      for (int tt = 0; tt < 512; tt++){ pfx[wg*512+tt] = run; if (padl[tt] == 0) run++; }
      cntp[wg] = run;
    }
    __syncthreads();
  }
  GBall();

  // persistent ownership
  const int l  = tid & 63, wv = tid >> 6;
  const int n2 = wv >> 1, k2 = wv & 1;    // wave roles: gate-pair x K-half
  const int kl = (l>>4) << 3;
  const int ar = rg*16 + (l&15);          // A row (batch)
  float cst = 0.f;                        // cell state, this thread owns (row,unit)
  float accN = 0.f, accC = 0.f;

  // ================= encoder =================
  { // preload enc weight slice to LDS (XOR swizzle)
    const int chunks = KE/8;
    for (int idx = tid; idx < 64*chunks; idx += NT){
      int s = idx / chunks, cc = idx - s*chunks;
      int grow = (s>>4)*512 + cg*16 + (s&15);
      uint4 v = *(const uint4*)(wenc + (size_t)grow*KE + cc*8);
      int byte = s*(KE*2) + cc*16; byte ^= (s&7)<<4;
      *(uint4*)(sm + byte) = v;
    }
  }
  __syncthreads();

  for (int t = 0; t < Lc; t++){
    const u16* hold = hbf + (t&1)*Bv*Hd;
    u16* hnew       = hbf + ((t+1)&1)*Bv*Hd;
    f4 acc0 = {0.f,0.f,0.f,0.f}, acc1 = {0.f,0.f,0.f,0.f};
    for (int ks = 0; ks < 10; ks++){
      int k = k2*320 + ks*32 + kl;
      s8 a;
      if (k < 128) a = cvt8(p.C + ((size_t)ar*Lc + t)*Vc + k);
      else         a = *(const s8*)(hold + ar*Hd + (k-128));
      acc0 = MM(a, ldsB(sm, KE, (n2*2+0)*16 + (l&15), k), acc0);
      acc1 = MM(a, ldsB(sm, KE, (n2*2+1)*16 + (l&15), k), acc1);
    }
    float* exch = (float*)(sm + SM_U);
    #pragma unroll
    for (int r = 0; r < 4; r++){
      int row = ((l>>4)<<2) + r;
      exch[((k2*4 + n2*2+0)*16 + row)*16 + (l&15)] = acc0[r];
      exch[((k2*4 + n2*2+1)*16 + row)*16 + (l&15)] = acc1[r];
    }
    __syncthreads();
    {
      int row = tid >> 4, u = tid & 15;
      int gb = cg*16 + u;
      float gi = exch[((0)*16+row)*16+u] + exch[((4)*16+row)*16+u] + be[0*512+gb];
      float gf = exch[((1)*16+row)*16+u] + exch[((5)*16+row)*16+u] + be[1*512+gb];
      float gg = exch[((2)*16+row)*16+u] + exch[((6)*16+row)*16+u] + be[2*512+gb];
      float go = exch[((3)*16+row)*16+u] + exch[((7)*16+row)*16+u] + be[3*512+gb];
      float fi = sigm(gi), ff = sigm(gf), fg = tanhf(gg), fo = sigm(go);
      cst = ff*cst + fi*fg;
      float hn = fo * tanhf(cst);
      int b = rg*16 + row;
      u16 hb = f2bf(hn);
      hnew[b*Hd + gb] = hb;
      if (p.Cpad[b*Lc + t] == 0){
        u32 pos = pfx[b*Lc + t];
        encc[((size_t)b*Lc + pos)*Hd + gb] = hb;
      }
    }
    RGB();
  }

  // ================= decoder =================
  { // preload dec weight slice
    const int chunks = KD/8;
    for (int idx = tid; idx < 64*chunks; idx += NT){
      int s = idx / chunks, cc = idx - s*chunks;
      int grow = (s>>4)*512 + cg*16 + (s&15);
      uint4 v = *(const uint4*)(wdec + (size_t)grow*KD + cc*8);
      int byte = s*(KD*2) + cc*16; byte ^= (s&7)<<4;
      *(uint4*)(sm + byte) = v;
    }
  }
  __syncthreads();

  for (int t = 0; t < Le-1; t++){
    const u16* hold = hbf + (t&1)*Bv*Hd;
    u16* hnew       = hbf + ((t+1)&1)*Bv*Hd;

    // ---- S1: gates GEMM + cell ----
    {
      f4 acc0 = {0.f,0.f,0.f,0.f}, acc1 = {0.f,0.f,0.f,0.f};
      for (int ks = 0; ks < 18; ks++){
        int k = k2*576 + ks*32 + kl;
        s8 a;
        if (k < 128)      a = cvt8(p.Eemb + ((size_t)ar*Le + t)*Vc + k);
        else if (k < 640) a = *(const s8*)(vpv  + ar*Hd + (k-128));
        else              a = *(const s8*)(hold + ar*Hd + (k-640));
        acc0 = MM(a, ldsB(sm, KD, (n2*2+0)*16 + (l&15), k), acc0);
        acc1 = MM(a, ldsB(sm, KD, (n2*2+1)*16 + (l&15), k), acc1);
      }
      float* exch = (float*)(sm + SM_U);
      #pragma unroll
      for (int r = 0; r < 4; r++){
        int row = ((l>>4)<<2) + r;
        exch[((k2*4 + n2*2+0)*16 + row)*16 + (l&15)] = acc0[r];
        exch[((k2*4 + n2*2+1)*16 + row)*16 + (l&15)] = acc1[r];
      }
      __syncthreads();
      {
        int row = tid >> 4, u = tid & 15;
        int gb = cg*16 + u;
        float gi = exch[((0)*16+row)*16+u] + exch[((4)*16+row)*16+u] + bd[0*512+gb];
        float gf = exch[((1)*16+row)*16+u] + exch[((5)*16+row)*16+u] + bd[1*512+gb];
        float gg = exch[((2)*16+row)*16+u] + exch[((6)*16+row)*16+u] + bd[2*512+gb];
        float go = exch[((3)*16+row)*16+u] + exch[((7)*16+row)*16+u] + bd[3*512+gb];
        float fi = sigm(gi), ff = sigm(gf), fg = tanhf(gg), fo = sigm(go);
        cst = ff*cst + fi*fg;
        float hn = fo * tanhf(cst);
        hnew[(rg*16+row)*Hd + gb] = f2bf(hn);
      }
    }
    RGB();

    // ---- S2: q = h_new @ attW^T ----
    if (tid < 64){
      f4 acc = {0.f,0.f,0.f,0.f};
      for (int ks = 0; ks < 16; ks++){
        int k = ks*32 + kl;
        s8 a  = *(const s8*)(hnew + (rg*16 + (l&15))*Hd + k);
        s8 bb = *(const s8*)(attw + (size_t)(cg*16 + (l&15))*Hd + k);
        acc = MM(a, bb, acc);
      }
      #pragma unroll
      for (int r = 0; r < 4; r++){
        int b = rg*16 + ((l>>4)<<2) + r;
        qg[b*Hd + cg*16 + (l&15)] = acc[r];
      }
    }
    RGB();

    // ---- S3: flash attention partials (2 WGs per row, rowgroup-local) ----
    {
      const int row = rg*16 + (cg >> 1), half = cg & 1;
      const int cn = (int)cntp[row], c2 = cn >> 1;
      const int st = half ? c2 : 0, en = half ? cn : c2, n = en - st;
      float* qld = (float*)(sm + SM_U);            // permuted q row
      float* scl = (float*)(sm + SM_U + 2048);     // scores -> weights
      float* red = (float*)(sm + SM_U + 3072);
      for (int i = tid; i < 512; i += NT)
        qld[i] = qg[row*Hd + ((i&31)*16 + (i>>5))];
      __syncthreads();
      const int sub = tid >> 5, ln = tid & 31;
      for (int i = sub; i < n; i += 8){
        const u16* e = encc + ((size_t)row*Lc + st + i)*Hd + ln*16;
        s8 ev0 = *(const s8*)(e);
        s8 ev1 = *(const s8*)(e + 8);
        float s = 0.f;
        #pragma unroll
        for (int j = 0; j < 8; j++) s += bf2f((u16)ev0[j]) * qld[j*32 + ln];
        #pragma unroll
        for (int j = 0; j < 8; j++) s += bf2f((u16)ev1[j]) * qld[(j+8)*32 + ln];
        #pragma unroll
        for (int m = 1; m < 32; m <<= 1) s += __shfl_xor(s, m, 64);
        if (ln == 0) scl[i] = s;
      }
      __syncthreads();
      float mloc = -1e30f;
      for (int i = tid; i < n; i += NT) mloc = fmaxf(mloc, scl[i]);
      mloc = wredmax(mloc);
      if ((tid&63) == 0) red[tid>>6] = mloc;
      __syncthreads();
      float M = fmaxf(fmaxf(red[0],red[1]), fmaxf(red[2],red[3]));
      __syncthreads();
      float sloc = 0.f;
      for (int i = tid; i < n; i += NT){ float w = expf(scl[i]-M); scl[i] = w; sloc += w; }
      sloc = wredsum(sloc);
      if ((tid&63) == 0) red[tid>>6] = sloc;
      __syncthreads();
      float S = red[0]+red[1]+red[2]+red[3];
      float a0 = 0.f, a1 = 0.f;
      const int h0 = tid*2;
      const u16* eb = encc + ((size_t)row*Lc + st)*Hd + h0;
      for (int i = 0; i < n; i++){
        float w = scl[i];
        u32 ev = *(const u32*)(eb + (size_t)i*Hd);
        a0 += w * bf2f((u16)(ev & 0xffffu));
        a1 += w * bf2f((u16)(ev >> 16));
      }
      pacc[(size_t)lid*Hd + h0]   = a0;
      pacc[(size_t)lid*Hd + h0+1] = a1;
      if (tid == 0){ pm[lid] = M; ps[lid] = S; }
    }
    RGB();

    // ---- S4: combine + Vnew + logits + CE (rowgroup leader cg==0) ----
    if (cg == 0){
      const int b0 = rg*16;
      float* sc4 = (float*)(sm + SM_U + 3072);
      if (tid < 16){
        int l1 = rg*32 + 2*tid;
        float m1 = pm[l1], m2 = pm[l1+1], s1 = ps[l1], s2 = ps[l1+1];
        float M = fmaxf(m1, m2);
        float e1 = expf(m1-M), e2 = expf(m2-M);
        float den = s1*e1 + s2*e2;
        sc4[tid*2]   = e1/den;
        sc4[tid*2+1] = e2/den;
      }
      __syncthreads();
      for (int idx = tid; idx < 16*512; idx += NT){
        int row = idx >> 9, h = idx & 511, b = b0 + row;
        int l1 = rg*32 + 2*row;
        float v = pacc[(size_t)l1*Hd + h]*sc4[row*2] + pacc[(size_t)(l1+1)*Hd + h]*sc4[row*2+1];
        attnb[b*Hd + h] = f2bf(v);
      }
      __syncthreads();
      // Vnew = [h, attn] @ outW^T + out_b
      f4 vac[8];
      #pragma unroll
      for (int nn = 0; nn < 8; nn++){
        float ob = p.outb[(wv*8+nn)*16 + (l&15)];
        f4 z = {ob,ob,ob,ob}; vac[nn] = z;
      }
      for (int ks = 0; ks < 32; ks++){
        int k = ks*32 + kl;
        s8 a = (k < 512) ? *(const s8*)(hnew  + (b0+(l&15))*Hd + k)
                         : *(const s8*)(attnb + (b0+(l&15))*Hd + (k-512));
        #pragma unroll
        for (int nn = 0; nn < 8; nn++){
          int ncol = (wv*8+nn)*16 + (l&15);
          s8 bb = *(const s8*)(outw + (size_t)ncol*1024 + k);
          vac[nn] = MM(a, bb, vac[nn]);
        }
      }
      #pragma unroll
      for (int nn = 0; nn < 8; nn++){
        #pragma unroll
        for (int r = 0; r < 4; r++){
          int ncol = (wv*8+nn)*16 + (l&15);
          int b = b0 + ((l>>4)<<2) + r;
          float v = vac[nn][r];
          vpv[b*Hd + ncol] = f2bf(v);
          tnh[b*Hd + ncol] = f2bf(tanhf(v));
        }
      }
      __syncthreads();
      // logits = tanh(Vnew) @ vocW^T + voc_b
      float* lg = (float*)(sm + SM_U);
      f4 lac[2];
      #pragma unroll
      for (int v2 = 0; v2 < 2; v2++){
        float vb = p.vocb[(wv*2+v2)*16 + (l&15)];
        f4 z = {vb,vb,vb,vb}; lac[v2] = z;
      }
      for (int ks = 0; ks < 16; ks++){
        int k = ks*32 + kl;
        s8 a = *(const s8*)(tnh + (b0+(l&15))*Hd + k);
        #pragma unroll
        for (int v2 = 0; v2 < 2; v2++){
          int vcol = (wv*2+v2)*16 + (l&15);
          s8 bb = *(const s8*)(vocw + (size_t)vcol*Hd + k);
          lac[v2] = MM(a, bb, lac[v2]);
        }
      }
      #pragma unroll
      for (int v2 = 0; v2 < 2; v2++){
        #pragma unroll
        for (int r = 0; r < 4; r++){
          int vcol = (wv*2+v2)*16 + (l&15);
          int row = ((l>>4)<<2) + r;
          lg[row*128 + vcol] = lac[v2][r];
        }
      }
      __syncthreads();
      // CE
      {
        int row = tid >> 4, i = tid & 15;
        int b = b0 + row;
        float lm = -1e30f;
        #pragma unroll
        for (int j = 0; j < 8; j++) lm = fmaxf(lm, lg[row*128 + i*8 + j]);
        #pragma unroll
        for (int m = 1; m < 16; m <<= 1) lm = fmaxf(lm, __shfl_xor(lm, m, 64));
        float le = 0.f;
        #pragma unroll
        for (int j = 0; j < 8; j++) le += expf(lg[row*128 + i*8 + j] - lm);
        #pragma unroll
        for (int m = 1; m < 16; m <<= 1) le += __shfl_xor(le, m, 64);
        if (i == 0){
          int tgt = p.E[b*Le + (t+1)];
          float lt = lg[row*128 + tgt];
          if (tgt != 0){ accN += logf(le) + lm - lt; accC += 1.f; }
        }
      }
    }
    RGB();
  }

  // ================= loss =================
  if (cg == 0 && (tid&15) == 0){
    atomicAdd(losp + 0, accN);
    atomicAdd(losp + 1, accC);
  }
  GBall();
  if (wg == 0 && tid == 0) p.out[0] = losp[0] / fmaxf(losp[1], 1.f);
}

extern "C" void kernel_launch(void* const* d_in, const int* in_sizes, int n_in,
                              void* d_out, int out_size, void* d_ws, size_t ws_size,
                              hipStream_t stream)
{
  hipFuncSetAttribute(reinterpret_cast<const void*>(k_main),
                      hipFuncAttributeMaxDynamicSharedMemorySize, SM_BYTES);
  hipMemsetAsync(d_ws, 0, 2048, stream);   // barrier counters reset every call

  P prm;
  prm.C    = (const float*)d_in[0];
  prm.Cpad = (const int*)  d_in[1];
  prm.E    = (const int*)  d_in[2];
  prm.Eemb = (const float*)d_in[3];
  prm.eWih = (const float*)d_in[4];
  prm.eWhh = (const float*)d_in[5];
  prm.ebih = (const float*)d_in[6];
  prm.ebhh = (const float*)d_in[7];
  prm.dWih = (const float*)d_in[8];
  prm.dWhh = (const float*)d_in[9];
  prm.dbih = (const float*)d_in[10];
  prm.dbhh = (const float*)d_in[11];
  prm.attW = (const float*)d_in[12];
  prm.outW = (const float*)d_in[13];
  prm.outb = (const float*)d_in[14];
  prm.vocW = (const float*)d_in[15];
  prm.vocb = (const float*)d_in[16];
  prm.ws   = (char*)d_ws;
  prm.out  = (float*)d_out;

  k_main<<<dim3(NWG), dim3(NT), SM_BYTES, stream>>>(prm);
}